// Round 4
// baseline (1287.418 us; speedup 1.0000x reference)
//
#include <hip/hip_runtime.h>
#include <cstdint>
#include <cstddef>

#define NN 16
#define DD 2048
#define BB 4096

#define TM 128
#define TN 128
#define BK 64
// LDS: B-only triple buffer, 3 x (TN*BK) halves = 3 x 16 KB = 48 KB.
// A never touches LDS (register-direct from MFMA-tiled S layout).
#define BBUF (TN * BK)

typedef _Float16 half8 __attribute__((ext_vector_type(8)));
typedef _Float16 half4 __attribute__((ext_vector_type(4)));
typedef float f32x4 __attribute__((ext_vector_type(4)));

// Tiled S layout: [m/16][k/32] blocks of 512 halves; within a block,
// offset = ((m&15) + 16*((k>>3)&3))*8 + (k&7). This is exactly the MFMA
// A-fragment per-lane layout, so a wave's A-frag load is 1 KB contiguous.
__device__ __forceinline__ size_t tiled_off(int m, int k) {
  return ((size_t)(m >> 4) * (DD / 32) + (k >> 5)) * 512 +
         (size_t)(((m & 15) + ((k >> 3) & 3) * 16) * 8);
}

__device__ __forceinline__ float fast_tanh(float x) {
  float ax = __builtin_fabsf(x);
  float e = __expf(-2.0f * ax);
  float t = (1.0f - e) / (1.0f + e);
  return x < 0.0f ? -t : t;
}

// W fp32 [i][k][n] -> Wh fp16 [i][n][k].  Register 8x8 micro-transpose,
// no LDS (old version had a 16-way bank conflict on 2B ds_writes).
__global__ __launch_bounds__(256) void wconv_kernel(const float* __restrict__ W,
                                                    _Float16* __restrict__ Wh) {
  const int i = blockIdx.z;
  const int k0 = blockIdx.y * 128;
  const int n0 = blockIdx.x * 128;
  const float* Wi = W + (size_t)i * DD * DD;
  _Float16* Whi = Wh + (size_t)i * DD * DD;
  const int t = threadIdx.x;
  const int kg = (t >> 4) * 8;
  const int ng = (t & 15) * 8;
  float4 v[8][2];
#pragma unroll
  for (int r = 0; r < 8; ++r) {
    const float* p = Wi + (size_t)(k0 + kg + r) * DD + n0 + ng;
    v[r][0] = *(const float4*)p;
    v[r][1] = *(const float4*)(p + 4);
  }
#pragma unroll
  for (int j = 0; j < 8; ++j) {
    half8 o;
#pragma unroll
    for (int r = 0; r < 8; ++r) {
      float e = (j < 4) ? ((const float*)&v[r][0])[j] : ((const float*)&v[r][1])[j - 4];
      o[r] = (_Float16)e;
    }
    *(half8*)(Whi + (size_t)(n0 + ng + j) * DD + k0 + kg) = o;
  }
}

// x fp32 -> S0 fp16 in tiled layout
__global__ __launch_bounds__(256) void xconv_kernel(const float* __restrict__ x,
                                                    _Float16* __restrict__ s0) {
  int gid = blockIdx.x * 256 + threadIdx.x;  // one half8 per thread
  int m = gid >> 8;          // DD/8 = 256 chunks per row
  int c8 = gid & 255;
  const float* p = x + (size_t)m * DD + c8 * 8;
  float4 v0 = *(const float4*)p;
  float4 v1 = *(const float4*)(p + 4);
  half8 o;
  o[0] = (_Float16)v0.x; o[1] = (_Float16)v0.y; o[2] = (_Float16)v0.z; o[3] = (_Float16)v0.w;
  o[4] = (_Float16)v1.x; o[5] = (_Float16)v1.y; o[6] = (_Float16)v1.z; o[7] = (_Float16)v1.w;
  *(half8*)(s0 + tiled_off(m, c8 * 8)) = o;
}

// One DAG node: out = tanh(S @ Wt^T + bias).
// 128x128 tile, 256 threads (4 waves 2Mx2N, each 64x64), BK=64.
// A: register-direct from tiled-S (global->VGPR, one K-tile prefetch depth,
//    no LDS, no barrier coupling). B: LDS triple-buffer via global_load_lds,
//    one s_barrier + counted vmcnt per K-tile (never 0 until tail).
// Hazard ledger (per-thread VMEM issue order pinned by sched_barrier(0)):
//   iter i issues A(i+1) x8 then B(i+2) x4. At end-of-iter publish of B(i+1)
//   (issued iter i-1, newest of that iter): younger = A(i+1)8 + B(i+2)4 = 12
//   -> vmcnt(12) retires B(i+1), keeps prefetches in flight. Tail i=30:
//   younger-than-B(31) = A(31)8 -> vmcnt(8). B-stage(i+2) writes buf
//   (i+2)%3 = (i-1)%3, last read in iter i-1 which ended at a barrier.
// 512 blocks @ 2 blocks/CU (48 KB LDS) -> two independent blocks per CU.
__global__ __launch_bounds__(256, 2) void node_gemm(
    const _Float16* __restrict__ S,      // [BB/16][DD/32][512] tiled fp16
    const _Float16* __restrict__ Wt,     // [DD][DD] fp16, layout [n][k]
    const float* __restrict__ bias,      // [DD]
    _Float16* __restrict__ Y,            // [BB][DD] fp16 row-major tanh output
    const _Float16* __restrict__ Yprev,  // row-major, may be null (node 0)
    _Float16* __restrict__ Snext,        // tiled fp16 next-node input
    float* __restrict__ Ofinal)          // non-null only for terminal node
{
  __shared__ _Float16 smem[3 * BBUF];  // 48 KB

  const int t = threadIdx.x;
  const int lane = t & 63;
  const int wave = t >> 6;
  const int bid = blockIdx.x;
  // XCD-aware bijective map: m-idx = xcd[1:0]*8 + loc[2:0] (32 m-tiles),
  // n-idx = xcd[2]*8 + loc[5:3] (16 n-tiles). Per-XCD K-slice ~256 KB in L2.
  const int xcd = bid & 7;
  const int loc = bid >> 3;
  const int m0 = ((xcd & 3) * 8 + (loc & 7)) * TM;
  const int n0 = ((xcd >> 2) * 8 + (loc >> 3)) * TN;
  const int wm = (wave >> 1) * 64;  // wave tile: 64m x 64n
  const int wn = (wave & 1) * 64;
  const int lrow = lane & 15;
  const int lq = lane >> 4;

  f32x4 acc[4][4];
#pragma unroll
  for (int i = 0; i < 4; ++i)
#pragma unroll
    for (int j = 0; j < 4; ++j) acc[i][j] = (f32x4)0.0f;

  // A-fragment base pointers: one tiled 16x32 block per (mt); a wave-load of
  // 64 lanes x 16 B = the whole 1 KB block, contiguous.
  const _Float16* Ab[4];
#pragma unroll
  for (int mt = 0; mt < 4; ++mt)
    Ab[mt] = S + ((size_t)((m0 + wm) >> 4) + mt) * (DD / 32) * 512 + (size_t)lane * 8;

  // B staging: thread t covers rows (t>>3)+32r (r=0..3), 16B chunk c = t&7.
  // XOR swizzle: LDS[row][c*8..] holds global k-chunk (c ^ (row&7)).
  const int srow = t >> 3;
  const int ska = ((t & 7) ^ (srow & 7)) * 8;
  const _Float16* bg = Wt + (size_t)(n0 + srow) * DD + ska;

  auto stageB = [&](int p, int k0) {
    const _Float16* b = bg + k0;
    _Float16* bl = smem + p * BBUF + t * 8;
#pragma unroll
    for (int r = 0; r < 4; ++r)
      __builtin_amdgcn_global_load_lds(
          (const __attribute__((address_space(1))) void*)(b + (size_t)(r * 32) * DD),
          (__attribute__((address_space(3))) void*)(bl + r * 2048), 16, 0, 0);
  };

  half8 aRa[8], aRb[8];
  int bcur = 0, bnxt = 2;

  // Prologue: A(0) -> regs; B(0), B(1) -> LDS. vmcnt(4) retires B(0)
  // (younger: B(1)x4), keeps B(1) in flight. A(0) waits are compiler-inserted.
#pragma unroll
  for (int mt = 0; mt < 4; ++mt)
#pragma unroll
    for (int ks = 0; ks < 2; ++ks)
      aRa[mt * 2 + ks] = *(const half8*)(Ab[mt] + (size_t)ks * 512);
  __builtin_amdgcn_sched_barrier(0);
  stageB(0, 0);
  stageB(1, BK);
  __builtin_amdgcn_sched_barrier(0);
  asm volatile("s_waitcnt vmcnt(4)" ::: "memory");
  asm volatile("s_barrier" ::: "memory");

  auto body = [&](int i, half8(&acur)[8], half8(&anxt)[8]) {
    // A(i+1) -> registers (plain loads; compiler tracks waits).
    if (i <= 30) {
#pragma unroll
      for (int mt = 0; mt < 4; ++mt)
#pragma unroll
        for (int ks = 0; ks < 2; ++ks)
          anxt[mt * 2 + ks] =
              *(const half8*)(Ab[mt] + (size_t)(2 * (i + 1) + ks) * 512);
    }
    __builtin_amdgcn_sched_barrier(0);
    if (i <= 29) stageB(bnxt, (i + 2) * BK);
    const _Float16* Bp = smem + bcur * BBUF;
#pragma unroll
    for (int ks = 0; ks < 2; ++ks) {
      const int cx = (((ks << 2) + lq) ^ (lrow & 7)) * 8;
      half8 b[4];
#pragma unroll
      for (int nt = 0; nt < 4; ++nt)
        b[nt] = *(const half8*)(Bp + (wn + nt * 16 + lrow) * BK + cx);
      __builtin_amdgcn_s_setprio(1);
#pragma unroll
      for (int mt = 0; mt < 4; ++mt)
#pragma unroll
        for (int nt = 0; nt < 4; ++nt)
          acc[mt][nt] = __builtin_amdgcn_mfma_f32_16x16x32_f16(
              acur[mt * 2 + ks], b[nt], acc[mt][nt], 0, 0, 0);
      __builtin_amdgcn_s_setprio(0);
    }
    // Publish B(i+1); keep A(i+1)+B(i+2) in flight.
    if (i <= 29) {
      asm volatile("s_waitcnt vmcnt(12)" ::: "memory");
      asm volatile("s_barrier" ::: "memory");
    } else if (i == 30) {
      asm volatile("s_waitcnt vmcnt(8)" ::: "memory");
      asm volatile("s_barrier" ::: "memory");
    }
    bcur = (bcur == 2) ? 0 : bcur + 1;
    bnxt = (bnxt == 2) ? 0 : bnxt + 1;
  };

  for (int ii = 0; ii < DD / BK; ii += 2) {
    body(ii, aRa, aRb);
    body(ii + 1, aRb, aRa);
  }

  // Epilogue: acc -> LDS CT [128][128] fp16 -> coalesced stores.
  __syncthreads();
  _Float16* CT = smem;  // 32 KB, fits in 48 KB
  float bv[4];
#pragma unroll
  for (int nt = 0; nt < 4; ++nt) bv[nt] = bias[n0 + wn + nt * 16 + lrow];
#pragma unroll
  for (int mt = 0; mt < 4; ++mt)
#pragma unroll
    for (int nt = 0; nt < 4; ++nt)
#pragma unroll
      for (int r = 0; r < 4; ++r) {
        int row = wm + mt * 16 + lq * 4 + r;
        int col = wn + nt * 16 + lrow;
        CT[row * TN + col] = (_Float16)fast_tanh(acc[mt][nt][r] + bv[nt]);
      }
  __syncthreads();

#pragma unroll
  for (int pp = 0; pp < 8; ++pp) {
    int idx = pp * 2048 + t * 8;
    int row = idx >> 7;
    int col = idx & 127;
    int gm = m0 + row;
    int gn = n0 + col;  // 8-aligned
    size_t off = (size_t)gm * DD + gn;
    half8 y = *(const half8*)&CT[idx];
    if (Ofinal) {
      float4 f0 = {(float)y[0], (float)y[1], (float)y[2], (float)y[3]};
      float4 f1 = {(float)y[4], (float)y[5], (float)y[6], (float)y[7]};
      *(float4*)(Ofinal + off) = f0;
      *(float4*)(Ofinal + off + 4) = f1;
    } else {
      *(half8*)(Y + off) = y;  // row-major (for Yprev-add of node i+1)
      half8 s = y;
      if (Yprev) s = s + *(const half8*)(Yprev + off);
      *(half8*)(Snext + tiled_off(gm, gn)) = s;  // tiled (next node's A)
    }
  }
}

extern "C" void kernel_launch(void* const* d_in, const int* in_sizes, int n_in,
                              void* d_out, int out_size, void* d_ws, size_t ws_size,
                              hipStream_t stream) {
  const float* x = (const float*)d_in[0];
  const float* W = (const float*)d_in[1];
  const float* b = (const float*)d_in[2];
  float* out = (float*)d_out;
  char* ws = (char*)d_ws;

  _Float16* Wh = (_Float16*)ws;  // 128 MB
  size_t wbytes = (size_t)NN * DD * DD * sizeof(_Float16);
  _Float16* S0 = (_Float16*)(ws + wbytes);
  _Float16* S1 = S0 + (size_t)BB * DD;
  _Float16* Y0 = S1 + (size_t)BB * DD;
  _Float16* Y1 = Y0 + (size_t)BB * DD;

  wconv_kernel<<<dim3(DD / 128, DD / 128, NN), dim3(256), 0, stream>>>(W, Wh);
  xconv_kernel<<<dim3((BB * DD) / (256 * 8)), dim3(256), 0, stream>>>(x, S0);

  _Float16* Sb[2] = {S0, S1};
  _Float16* Yb[2] = {Y0, Y1};
  dim3 ggrid((BB / TM) * (DD / TN));  // 32 x 16 = 512 blocks = 2/CU
  for (int i = 0; i < NN; ++i) {
    const _Float16* Sin = Sb[i & 1];
    _Float16* Sout = Sb[(i + 1) & 1];
    _Float16* Yout = Yb[i & 1];
    const _Float16* Yp = (i >= 1) ? Yb[(i + 1) & 1] : nullptr;
    const bool last = (i == NN - 1);
    node_gemm<<<ggrid, dim3(256), 0, stream>>>(Sin, Wh + (size_t)i * DD * DD,
                                               b + (size_t)i * DD, Yout, Yp, Sout,
                                               last ? out : nullptr);
  }
  (void)in_sizes; (void)n_in; (void)out_size; (void)ws_size;
}